// Round 21
// baseline (343.330 us; speedup 1.0000x reference)
//
#include <hip/hip_runtime.h>

#define DD 64
#define NPB 16     // nodes per tile (4 waves x 4 concurrent nodes in prop)
#define NBKMAX 128 // max coarse buckets (N <= 131072)
#define CAPB 20480 // bucket capacity (mean 16384 + 32 sigma)
#define EPB 8      // edges per thread in histA
#define EPT 20     // entries per thread in csrB (CAPB/1024)
#define ASTR 72    // halves per LDS A-tile row (64 + 8 pad)

typedef _Float16 f16x8 __attribute__((ext_vector_type(8)));
typedef float f32x4 __attribute__((ext_vector_type(4)));

// ---- histA: coarse dst-bucket scatter + src-degree u8 partial histogram ----
// One edge pass: dst entries -> bktbuf (ranked via LDS), src counts -> srcp row.
__global__ __launch_bounds__(1024) void histA_kernel(
        const int* __restrict__ src, const int* __restrict__ dst,
        int* __restrict__ gbcnt, unsigned int* __restrict__ bktbuf,
        unsigned char* __restrict__ srcp, int NR,
        int E, int nbk) {
    extern __shared__ unsigned int ldsH[];     // NR/4 words u8 src counters
    __shared__ int lcnt[NBKMAX];
    __shared__ int lbase[NBKMAX];
    int nw = NR >> 2;
    int t = threadIdx.x;
    for (int i = t; i < nw; i += 1024) ldsH[i] = 0u;
    if (t < NBKMAX) lcnt[t] = 0;
    __syncthreads();
    int base = blockIdx.x * (EPB * 1024);
    unsigned int ent[EPB];
    int rk[EPB];
    int bk[EPB];
    #pragma unroll
    for (int k = 0; k < EPB; ++k) {
        int e = base + t + k * 1024;
        bk[k] = -1;
        if (e < E) {
            int s = __builtin_nontemporal_load(src + e);
            int d = __builtin_nontemporal_load(dst + e);
            atomicAdd(&ldsH[s >> 2], 1u << ((unsigned int)(s & 3) * 8u));
            int b = d >> 10;
            ent[k] = ((unsigned int)s << 10) | (unsigned int)(d & 1023);
            rk[k] = atomicAdd(&lcnt[b], 1);
            bk[k] = b;
        }
    }
    __syncthreads();
    if (t < nbk) lbase[t] = atomicAdd(&gbcnt[t], lcnt[t]);
    __syncthreads();
    #pragma unroll
    for (int k = 0; k < EPB; ++k) {
        if (bk[k] >= 0) {
            int pos = lbase[bk[k]] + rk[k];
            if (pos < CAPB)
                __builtin_nontemporal_store(ent[k],
                    bktbuf + (size_t)bk[k] * CAPB + pos);
        }
    }
    unsigned int* outp = reinterpret_cast<unsigned int*>(srcp + (size_t)blockIdx.x * NR);
    for (int i = t; i < nw; i += 1024) outp[i] = ldsH[i];
}

// ---- disred: dis[g] = rsqrt(deg) from na srcp partials ----
__global__ void disred_kernel(const unsigned char* __restrict__ srcp,
                              float* __restrict__ dis, int N, int NR, int na) {
    int g = blockIdx.x * 256 + threadIdx.x;
    if (g < N) {
        int degv = 0;
        for (int i = 0; i < na; ++i) degv += srcp[(size_t)i * NR + g];
        dis[g] = (degv > 0) ? rsqrtf((float)degv) : 0.0f;
    }
}

// ---- csrB: per-bucket CSR build entirely in LDS; coalesced adjS writeout ----
__global__ __launch_bounds__(1024) void csrB_kernel(
        const unsigned int* __restrict__ bktbuf, const int* __restrict__ gbcnt,
        int* __restrict__ rowptr, int* __restrict__ adjS,
        int N, int nbk, int E) {
    __shared__ int ncnt[1024];
    __shared__ int tmp[1024];
    __shared__ int adjstage[CAPB];
    __shared__ int bbase_s;
    int b = blockIdx.x;
    int t = threadIdx.x;
    if (t == 0) {
        int acc = 0;
        for (int i = 0; i < b; ++i) acc += gbcnt[i];
        bbase_s = acc;
    }
    ncnt[t] = 0;
    __syncthreads();
    int total = min(gbcnt[b], CAPB);
    int bbase = bbase_s;
    const unsigned int* bp = bktbuf + (size_t)b * CAPB;
    unsigned int sv[EPT];
    int rk[EPT];
    int dl[EPT];
    #pragma unroll
    for (int k = 0; k < EPT; ++k) {
        int i = t + k * 1024;
        dl[k] = -1;
        if (i < total) {
            unsigned int v = bp[i];
            sv[k] = v >> 10;
            int d = (int)(v & 1023u);
            dl[k] = d;
            rk[k] = atomicAdd(&ncnt[d], 1);
        }
    }
    __syncthreads();
    int v = ncnt[t];
    tmp[t] = v;
    __syncthreads();
    for (int off = 1; off < 1024; off <<= 1) {
        int a = (t >= off) ? tmp[t - off] : 0;
        __syncthreads();
        tmp[t] += a;
        __syncthreads();
    }
    int excl = tmp[t] - v;
    int node = b * 1024 + t;
    if (node < N) rowptr[node] = bbase + excl;
    if (b == nbk - 1 && t == 1023) rowptr[N] = E;
    __syncthreads();
    ncnt[t] = excl;
    __syncthreads();
    #pragma unroll
    for (int k = 0; k < EPT; ++k)
        if (dl[k] >= 0) adjstage[ncnt[dl[k]] + rk[k]] = (int)sv[k];
    __syncthreads();
    for (int i = t; i < total; i += 1024)
        adjS[bbase + i] = adjstage[i];
}

// ---- cvt: P0[node][64] = f * x[node][:], f = dis>0 ? dis : 1 (fp16) ----
__global__ void cvt_kernel(const float* __restrict__ x, const float* __restrict__ dis,
                           _Float16* __restrict__ p0, long long n8) {
    long long i = (long long)blockIdx.x * blockDim.x + threadIdx.x;
    if (i < n8) {
        int node = (int)(i >> 3);
        float dv = dis[node];
        float f = (dv > 0.f) ? dv : 1.0f;
        const float4* x4 = reinterpret_cast<const float4*>(x);
        float4 a = x4[i * 2], b = x4[i * 2 + 1];
        f16x8 h;
        h[0] = (_Float16)(f * a.x); h[1] = (_Float16)(f * a.y);
        h[2] = (_Float16)(f * a.z); h[3] = (_Float16)(f * a.w);
        h[4] = (_Float16)(f * b.x); h[5] = (_Float16)(f * b.y);
        h[6] = (_Float16)(f * b.z); h[7] = (_Float16)(f * b.w);
        reinterpret_cast<f16x8*>(p0)[i] = h;
    }
}

// ---- wcvt: pre-swizzle W into fp16 MFMA B-frag layout ----
__global__ void wcvt_kernel(const float* __restrict__ W, _Float16* __restrict__ Wh,
                            int nfrag) {
    int idx = blockIdx.x * blockDim.x + threadIdx.x;
    if (idx >= nfrag) return;
    int lane = idx & 63;
    int ct = (idx >> 6) & 3;
    int kt = (idx >> 8) & 1;
    int k = idx >> 9;
    int r0 = kt * 32 + (lane >> 4) * 8;
    int c = ct * 16 + (lane & 15);
    f16x8 h;
    #pragma unroll
    for (int i = 0; i < 8; ++i)
        h[i] = (_Float16)W[(size_t)k * DD * DD + (size_t)(r0 + i) * DD + c];
    reinterpret_cast<f16x8*>(Wh)[idx] = h;
}

// ---- prop: Pout = scale*dis^2*gathersum(Pin) - Pt0 ----
__global__ __launch_bounds__(256, 8) void prop_kernel(
        const int* __restrict__ rowptr, const int* __restrict__ adjS,
        const float* __restrict__ dis,
        const _Float16* __restrict__ h, const _Float16* t0,
        _Float16* __restrict__ pout, float scale, int N) {
    int t = threadIdx.x;
    int nl = t >> 6, lane = t & 63;
    int q = lane & 7;
    int s = (lane >> 3) & 1;
    int ng = lane >> 4;
    int node = blockIdx.x * NPB + nl * 4 + ng;
    bool valid = node < N;
    const f16x8* h8 = reinterpret_cast<const f16x8*>(h);

    int beg = 0, end = 0;
    if (valid) { beg = rowptr[node]; end = rowptr[node + 1]; }

    float acc[8];
    #pragma unroll
    for (int i = 0; i < 8; ++i) acc[i] = 0.f;

    int j = beg + s;
    int e0 = (j < end) ? adjS[j] : 0;
    int e1 = (j + 2 < end) ? adjS[j + 2] : 0;
    int e2 = (j + 4 < end) ? adjS[j + 4] : 0;
    int e3 = (j + 6 < end) ? adjS[j + 6] : 0;
    float m0 = (j < end) ? 1.f : 0.f;
    float m1 = (j + 2 < end) ? 1.f : 0.f;
    float m2 = (j + 4 < end) ? 1.f : 0.f;
    float m3 = (j + 6 < end) ? 1.f : 0.f;
    while (j < end) {
        int jn = j + 8;
        int n0 = (jn < end) ? adjS[jn] : 0;
        int n1 = (jn + 2 < end) ? adjS[jn + 2] : 0;
        int n2 = (jn + 4 < end) ? adjS[jn + 4] : 0;
        int n3 = (jn + 6 < end) ? adjS[jn + 6] : 0;
        float nm0 = (jn < end) ? 1.f : 0.f;
        float nm1 = (jn + 2 < end) ? 1.f : 0.f;
        float nm2 = (jn + 4 < end) ? 1.f : 0.f;
        float nm3 = (jn + 6 < end) ? 1.f : 0.f;
        f16x8 g0 = h8[(size_t)e0 * 8 + q];
        f16x8 g1 = h8[(size_t)e1 * 8 + q];
        f16x8 g2 = h8[(size_t)e2 * 8 + q];
        f16x8 g3 = h8[(size_t)e3 * 8 + q];
        #pragma unroll
        for (int i = 0; i < 8; ++i) {
            acc[i] += m0 * (float)g0[i] + m1 * (float)g1[i];
            acc[i] += m2 * (float)g2[i] + m3 * (float)g3[i];
        }
        e0 = n0; e1 = n1; e2 = n2; e3 = n3;
        m0 = nm0; m1 = nm1; m2 = nm2; m3 = nm3;
        j = jn;
    }
    #pragma unroll
    for (int i = 0; i < 8; ++i) acc[i] += __shfl_xor(acc[i], 8, 64);

    if (s == 0 && valid) {
        float dv = dis[node];
        float cf = scale * dv * dv;
        size_t base = (size_t)node * DD + q * 8;
        f16x8 vh;
        if (t0) {
            f16x8 t0v = __builtin_nontemporal_load(
                reinterpret_cast<const f16x8*>(t0 + base));
            #pragma unroll
            for (int i = 0; i < 8; ++i)
                vh[i] = (_Float16)(cf * acc[i] - (float)t0v[i]);
        } else {
            #pragma unroll
            for (int i = 0; i < 8; ++i) vh[i] = (_Float16)(cf * acc[i]);
        }
        *reinterpret_cast<f16x8*>(pout + base) = vh;   // plain: keep L2/L3-resident
    }
}

// ---- A-frag: row = node, k = kt*32 + lk*8 + i (contiguous 16B) ----
static __device__ __forceinline__ f16x8 afrag(const _Float16* __restrict__ P,
                                              int node, int kt, int lk) {
    return *reinterpret_cast<const f16x8*>(P + (size_t)node * DD + kt * 32 + lk * 8);
}

// ---- prop_last: P4 = -2 dis^2 gather(P3) - P2 (LDS tile, never written out);
//      out = b + invd*(P0@W0 + P1@W1 + P2@W2 + P3@W3 + P4@W4) ----
__global__ __launch_bounds__(256, 6) void prop_last_kernel(
        const int* __restrict__ rowptr, const int* __restrict__ adjS,
        const float* __restrict__ dis,
        const _Float16* __restrict__ h /*P3*/, const _Float16* __restrict__ t0 /*P2*/,
        const _Float16* __restrict__ P0, const _Float16* __restrict__ P1,
        const _Float16* __restrict__ Wh, const float* __restrict__ bias,
        float* __restrict__ out, int N) {
    __shared__ _Float16 A_lds[NPB][ASTR];
    int t = threadIdx.x;
    int nl = t >> 6, lane = t & 63;
    int q = lane & 7;
    int s = (lane >> 3) & 1;
    int ng = lane >> 4;
    int nb0 = blockIdx.x * NPB;
    int node = nb0 + nl * 4 + ng;
    bool valid = node < N;
    const f16x8* h8 = reinterpret_cast<const f16x8*>(h);

    int beg = 0, end = 0;
    if (valid) { beg = rowptr[node]; end = rowptr[node + 1]; }

    float acc[8];
    #pragma unroll
    for (int i = 0; i < 8; ++i) acc[i] = 0.f;

    int j = beg + s;
    int e0 = (j < end) ? adjS[j] : 0;
    int e1 = (j + 2 < end) ? adjS[j + 2] : 0;
    int e2 = (j + 4 < end) ? adjS[j + 4] : 0;
    int e3 = (j + 6 < end) ? adjS[j + 6] : 0;
    float m0 = (j < end) ? 1.f : 0.f;
    float m1 = (j + 2 < end) ? 1.f : 0.f;
    float m2 = (j + 4 < end) ? 1.f : 0.f;
    float m3 = (j + 6 < end) ? 1.f : 0.f;
    while (j < end) {
        int jn = j + 8;
        int n0 = (jn < end) ? adjS[jn] : 0;
        int n1 = (jn + 2 < end) ? adjS[jn + 2] : 0;
        int n2 = (jn + 4 < end) ? adjS[jn + 4] : 0;
        int n3 = (jn + 6 < end) ? adjS[jn + 6] : 0;
        float nm0 = (jn < end) ? 1.f : 0.f;
        float nm1 = (jn + 2 < end) ? 1.f : 0.f;
        float nm2 = (jn + 4 < end) ? 1.f : 0.f;
        float nm3 = (jn + 6 < end) ? 1.f : 0.f;
        f16x8 g0 = h8[(size_t)e0 * 8 + q];
        f16x8 g1 = h8[(size_t)e1 * 8 + q];
        f16x8 g2 = h8[(size_t)e2 * 8 + q];
        f16x8 g3 = h8[(size_t)e3 * 8 + q];
        #pragma unroll
        for (int i = 0; i < 8; ++i) {
            acc[i] += m0 * (float)g0[i] + m1 * (float)g1[i];
            acc[i] += m2 * (float)g2[i] + m3 * (float)g3[i];
        }
        e0 = n0; e1 = n1; e2 = n2; e3 = n3;
        m0 = nm0; m1 = nm1; m2 = nm2; m3 = nm3;
        j = jn;
    }
    #pragma unroll
    for (int i = 0; i < 8; ++i) acc[i] += __shfl_xor(acc[i], 8, 64);

    if (s == 0 && valid) {
        float dv = dis[node];
        float cf = -2.0f * dv * dv;
        size_t base = (size_t)node * DD + q * 8;
        f16x8 t0v = __builtin_nontemporal_load(
            reinterpret_cast<const f16x8*>(t0 + base));
        f16x8 vh;
        #pragma unroll
        for (int i = 0; i < 8; ++i)
            vh[i] = (_Float16)(cf * acc[i] - (float)t0v[i]);
        *reinterpret_cast<f16x8*>(&A_lds[nl * 4 + ng][q * 8]) = vh;
    }
    __syncthreads();

    // ---- GEMM epilogue: wave nl = col-tile ----
    int ct = nl, lr = lane & 15, lk = lane >> 4;
    const f16x8* Wh8 = reinterpret_cast<const f16x8*>(Wh);
    f16x8 bf[5][2];
    #pragma unroll
    for (int k = 0; k < 5; ++k)
        #pragma unroll
        for (int kt = 0; kt < 2; ++kt)
            bf[k][kt] = Wh8[((k * 2 + kt) * 4 + ct) * 64 + lane];
    int gn = min(nb0 + lr, N - 1);
    f32x4 d = {0.f, 0.f, 0.f, 0.f};
    #pragma unroll
    for (int kt = 0; kt < 2; ++kt) {
        f16x8 a4 = *reinterpret_cast<const f16x8*>(&A_lds[lr][kt * 32 + lk * 8]);
        d = __builtin_amdgcn_mfma_f32_16x16x32_f16(afrag(P0, gn, kt, lk), bf[0][kt], d, 0, 0, 0);
        d = __builtin_amdgcn_mfma_f32_16x16x32_f16(afrag(P1, gn, kt, lk), bf[1][kt], d, 0, 0, 0);
        d = __builtin_amdgcn_mfma_f32_16x16x32_f16(afrag(t0, gn, kt, lk), bf[2][kt], d, 0, 0, 0);
        d = __builtin_amdgcn_mfma_f32_16x16x32_f16(afrag(h,  gn, kt, lk), bf[3][kt], d, 0, 0, 0);
        d = __builtin_amdgcn_mfma_f32_16x16x32_f16(a4, bf[4][kt], d, 0, 0, 0);
    }
    int nvb = min(NPB, N - nb0);
    int col = ct * 16 + lr;
    float bv = bias[col];
    #pragma unroll
    for (int r = 0; r < 4; ++r) {
        int row = lk * 4 + r;
        if (row < nvb) {
            float dv = dis[nb0 + row];
            float invd = (dv > 0.f) ? 1.f / dv : 1.f;
            long long o = (long long)(nb0 + row) * DD + col;
            __builtin_nontemporal_store(bv + invd * d[r], out + o);
        }
    }
}

// ---- gemm2 (fallback): out = b + invd*(P0@W0 + P1@W1) ----
__global__ __launch_bounds__(256, 8) void gemm2_kernel(
        const _Float16* __restrict__ P0, const _Float16* __restrict__ P1,
        const float* __restrict__ dis,
        const float* __restrict__ W0, const float* __restrict__ W1,
        const float* __restrict__ bias, float* __restrict__ out, int N) {
    int t = threadIdx.x;
    int nl = t >> 6, lane = t & 63;
    int ct = nl, lr = lane & 15, lk = lane >> 4;
    f16x8 bf0[2], bf1[2];
    #pragma unroll
    for (int kt = 0; kt < 2; ++kt)
        #pragma unroll
        for (int i = 0; i < 8; ++i) {
            int r = kt * 32 + lk * 8 + i;
            bf0[kt][i] = (_Float16)W0[r * DD + ct * 16 + lr];
            bf1[kt][i] = (_Float16)W1[r * DD + ct * 16 + lr];
        }
    int nb0 = blockIdx.x * NPB;
    int node = min(nb0 + lr, N - 1);
    f32x4 d = {0.f, 0.f, 0.f, 0.f};
    #pragma unroll
    for (int kt = 0; kt < 2; ++kt) {
        d = __builtin_amdgcn_mfma_f32_16x16x32_f16(afrag(P0, node, kt, lk), bf0[kt], d, 0, 0, 0);
        d = __builtin_amdgcn_mfma_f32_16x16x32_f16(afrag(P1, node, kt, lk), bf1[kt], d, 0, 0, 0);
    }
    int nvb = min(NPB, N - nb0);
    int col = ct * 16 + lr;
    float bv = bias[col];
    #pragma unroll
    for (int r = 0; r < 4; ++r) {
        int row = lk * 4 + r;
        if (row < nvb) {
            float dv = dis[nb0 + row];
            float invd = (dv > 0.f) ? 1.f / dv : 1.f;
            long long o = (long long)(nb0 + row) * DD + col;
            out[o] = bv + invd * d[r];
        }
    }
}

// ---- gemm1 (fallback): out += invd*(P@Wk) ----
__global__ __launch_bounds__(256, 8) void gemm1_kernel(
        const _Float16* __restrict__ P, const float* __restrict__ dis,
        const float* __restrict__ Wk, float* __restrict__ out, int N) {
    int t = threadIdx.x;
    int nl = t >> 6, lane = t & 63;
    int ct = nl, lr = lane & 15, lk = lane >> 4;
    f16x8 bf[2];
    #pragma unroll
    for (int kt = 0; kt < 2; ++kt)
        #pragma unroll
        for (int i = 0; i < 8; ++i) {
            int r = kt * 32 + lk * 8 + i;
            bf[kt][i] = (_Float16)Wk[r * DD + ct * 16 + lr];
        }
    int nb0 = blockIdx.x * NPB;
    int node = min(nb0 + lr, N - 1);
    f32x4 d = {0.f, 0.f, 0.f, 0.f};
    #pragma unroll
    for (int kt = 0; kt < 2; ++kt)
        d = __builtin_amdgcn_mfma_f32_16x16x32_f16(afrag(P, node, kt, lk), bf[kt], d, 0, 0, 0);
    int nvb = min(NPB, N - nb0);
    int col = ct * 16 + lr;
    #pragma unroll
    for (int r = 0; r < 4; ++r) {
        int row = lk * 4 + r;
        if (row < nvb) {
            float dv = dis[nb0 + row];
            float invd = (dv > 0.f) ? 1.f / dv : 1.f;
            long long o = (long long)(nb0 + row) * DD + col;
            out[o] = out[o] + invd * d[r];
        }
    }
}

extern "C" void kernel_launch(void* const* d_in, const int* in_sizes, int n_in,
                              void* d_out, int out_size, void* d_ws, size_t ws_size,
                              hipStream_t stream) {
    const float* x  = (const float*)d_in[0];
    const int*   ei = (const int*)d_in[1];
    const float* W  = (const float*)d_in[2];
    const float* b  = (const float*)d_in[3];
    float* out = (float*)d_out;

    const int N = in_sizes[0] / DD;
    const int E = in_sizes[1] / 2;
    const int K = in_sizes[2] / (DD * DD);
    const long long ND = (long long)N * DD;
    const int NR = ((N + 3) / 4) * 4;
    const int nbk = (N + 1023) >> 10;             // coarse buckets (<= NBKMAX)
    const int na = (E + EPB * 1024 - 1) / (EPB * 1024);  // histA blocks

    const int* src = ei;
    const int* dst = ei + E;

    size_t off = 0;
    char* base = (char*)d_ws;
    auto alloc = [&](size_t bytes) {
        char* p = base + off;
        off = (off + bytes + 63) & ~(size_t)63;
        return p;
    };
    float* dis = (float*)alloc((size_t)N * 4);
    int* rowptr = (int*)alloc((size_t)(N + 1) * 4);
    _Float16* Wh = (_Float16*)alloc((size_t)5 * 2 * 4 * 64 * 8 * 2);
    int* gbcnt = (int*)alloc((size_t)NBKMAX * 4);
    // overlay region: srcp partials + bktbuf (dead after csrB/disred) host P2 later
    char* ovl = alloc((size_t)na * NR + (size_t)NBKMAX * CAPB * 4);
    unsigned char* srcp = (unsigned char*)ovl;
    unsigned int* bktbuf = (unsigned int*)(ovl + (size_t)na * NR);
    int* adjS = (int*)alloc((size_t)E * 4);
    _Float16* P0 = (_Float16*)alloc((size_t)ND * 2);
    _Float16* P1 = (_Float16*)alloc((size_t)ND * 2);
    _Float16* P3 = (_Float16*)alloc((size_t)ND * 2);
    _Float16* P2 = (_Float16*)ovl;      // overlays srcp+bktbuf after they're dead

    (void)hipMemsetAsync(gbcnt, 0, (size_t)NBKMAX * 4, stream);

    histA_kernel<<<na, 1024, (size_t)NR, stream>>>(src, dst, gbcnt, bktbuf,
                                                   srcp, NR, E, nbk);
    disred_kernel<<<(N + 255) / 256, 256, 0, stream>>>(srcp, dis, N, NR, na);
    csrB_kernel<<<nbk, 1024, 0, stream>>>(bktbuf, gbcnt, rowptr, adjS, N, nbk, E);

    const long long n8 = ND / 8;
    cvt_kernel<<<(int)((n8 + 255) / 256), 256, 0, stream>>>(x, dis, P0, n8);
    if (K == 5) {
        const int nfrag = 5 * 2 * 4 * 64;
        wcvt_kernel<<<(nfrag + 255) / 256, 256, 0, stream>>>(W, Wh, nfrag);
    }

    const int pgrid = (N + NPB - 1) / NPB;
    const int Wsz = DD * DD;

    if (K == 5) {
        prop_kernel<<<pgrid, 256, 0, stream>>>(rowptr, adjS, dis, P0,
                                               (const _Float16*)0, P1, -1.0f, N);
        prop_kernel<<<pgrid, 256, 0, stream>>>(rowptr, adjS, dis, P1, P0, P2, -2.0f, N);
        prop_kernel<<<pgrid, 256, 0, stream>>>(rowptr, adjS, dis, P2, P1, P3, -2.0f, N);
        // P4 in-LDS + full GEMM epilogue (out write-only)
        prop_last_kernel<<<pgrid, 256, 0, stream>>>(rowptr, adjS, dis, P3, P2,
                                                    P0, P1, Wh, b, out, N);
    } else {
        prop_kernel<<<pgrid, 256, 0, stream>>>(rowptr, adjS, dis, P0,
                                               (const _Float16*)0, P1, -1.0f, N);
        gemm2_kernel<<<pgrid, 256, 0, stream>>>(P0, P1, dis, W, W + Wsz, b, out, N);
        _Float16* t0 = P0;
        _Float16* h  = P1;
        _Float16* fr = P2;
        for (int k = 2; k < K; ++k) {
            prop_kernel<<<pgrid, 256, 0, stream>>>(rowptr, adjS, dis, h, t0, fr, -2.0f, N);
            gemm1_kernel<<<pgrid, 256, 0, stream>>>(fr, dis, W + (long long)k * Wsz,
                                                    out, N);
            _Float16* nfree = t0;
            t0 = h; h = fr; fr = nfree;
        }
    }
}

// Round 22
// 315.470 us; speedup vs baseline: 1.0883x; 1.0883x over previous
//
#include <hip/hip_runtime.h>

#define DD 64
#define NPB 16     // nodes per tile (4 waves x 4 concurrent nodes in prop)
#define NBS 256    // histS partial-histogram blocks (1 block/CU, use all CUs)
#define NBKMAX 128 // max coarse buckets (N <= 131072)
#define CAPB 20480 // bucket capacity (mean 16384 + 32 sigma)
#define EPB 8      // edges per thread in histA
#define EPT 20     // entries per thread in csrB (CAPB/1024)
#define ASTR 72    // halves per LDS A-tile row (64 + 8 pad)

typedef _Float16 f16x8 __attribute__((ext_vector_type(8)));
typedef float f32x4 __attribute__((ext_vector_type(4)));

// ---- histS: per-block LDS u8 histogram of src (for degrees) ----
__global__ __launch_bounds__(1024) void histS_kernel(
        const int* __restrict__ src, unsigned char* __restrict__ srcp,
        int N, int NR, int E, int slice) {
    extern __shared__ unsigned int ldsH[];
    int nw = NR >> 2;
    int t = threadIdx.x;
    for (int i = t; i < nw; i += 1024) ldsH[i] = 0u;
    __syncthreads();
    int base = blockIdx.x * slice;
    int end = min(base + slice, E);
    for (int e = base + t; e < end; e += 1024) {
        int s = __builtin_nontemporal_load(src + e);
        atomicAdd(&ldsH[s >> 2], 1u << ((unsigned int)(s & 3) * 8u));
    }
    __syncthreads();
    unsigned int* outp = reinterpret_cast<unsigned int*>(srcp + (size_t)blockIdx.x * NR);
    for (int i = t; i < nw; i += 1024) outp[i] = ldsH[i];
}

// ---- disred: dis[g] = rsqrt(deg) from NBS srcp partials ----
__global__ void disred_kernel(const unsigned char* __restrict__ srcp,
                              float* __restrict__ dis, int N, int NR) {
    int g = blockIdx.x * 256 + threadIdx.x;
    if (g < N) {
        int degv = 0;
        #pragma unroll 8
        for (int i = 0; i < NBS; ++i) degv += srcp[(size_t)i * NR + g];
        dis[g] = (degv > 0) ? rsqrtf((float)degv) : 0.0f;
    }
}

// ---- histA: coarse dst-bucket scatter (bucket = dst>>10) ----
__global__ __launch_bounds__(1024) void histA_kernel(
        const int* __restrict__ src, const int* __restrict__ dst,
        int* __restrict__ gbcnt, unsigned int* __restrict__ bktbuf,
        int E, int nbk) {
    __shared__ int lcnt[NBKMAX];
    __shared__ int lbase[NBKMAX];
    int t = threadIdx.x;
    if (t < NBKMAX) lcnt[t] = 0;
    __syncthreads();
    int base = blockIdx.x * (EPB * 1024);
    unsigned int ent[EPB];
    int rk[EPB];
    int bk[EPB];
    #pragma unroll
    for (int k = 0; k < EPB; ++k) {
        int e = base + t + k * 1024;
        bk[k] = -1;
        if (e < E) {
            int s = __builtin_nontemporal_load(src + e);
            int d = __builtin_nontemporal_load(dst + e);
            int b = d >> 10;
            ent[k] = ((unsigned int)s << 10) | (unsigned int)(d & 1023);
            rk[k] = atomicAdd(&lcnt[b], 1);
            bk[k] = b;
        }
    }
    __syncthreads();
    if (t < nbk) lbase[t] = atomicAdd(&gbcnt[t], lcnt[t]);
    __syncthreads();
    #pragma unroll
    for (int k = 0; k < EPB; ++k) {
        if (bk[k] >= 0) {
            int pos = lbase[bk[k]] + rk[k];
            if (pos < CAPB)
                __builtin_nontemporal_store(ent[k],
                    bktbuf + (size_t)bk[k] * CAPB + pos);
        }
    }
}

// ---- csrB: per-bucket CSR build entirely in LDS; coalesced adjS writeout ----
__global__ __launch_bounds__(1024) void csrB_kernel(
        const unsigned int* __restrict__ bktbuf, const int* __restrict__ gbcnt,
        int* __restrict__ rowptr, int* __restrict__ adjS,
        int N, int nbk, int E) {
    __shared__ int ncnt[1024];
    __shared__ int tmp[1024];
    __shared__ int adjstage[CAPB];
    __shared__ int gb[NBKMAX];
    __shared__ int bbase_s;
    int b = blockIdx.x;
    int t = threadIdx.x;
    if (t < NBKMAX) gb[t] = (t < nbk) ? gbcnt[t] : 0;
    ncnt[t] = 0;
    __syncthreads();
    if (t == 0) {
        int acc = 0;
        for (int i = 0; i < b; ++i) acc += gb[i];
        bbase_s = acc;
    }
    __syncthreads();
    int total = min(gb[b], CAPB);
    int bbase = bbase_s;
    const unsigned int* bp = bktbuf + (size_t)b * CAPB;
    unsigned int sv[EPT];
    int rk[EPT];
    int dl[EPT];
    #pragma unroll
    for (int k = 0; k < EPT; ++k) {
        int i = t + k * 1024;
        dl[k] = -1;
        if (i < total) {
            unsigned int v = bp[i];
            sv[k] = v >> 10;
            int d = (int)(v & 1023u);
            dl[k] = d;
            rk[k] = atomicAdd(&ncnt[d], 1);
        }
    }
    __syncthreads();
    int v = ncnt[t];
    tmp[t] = v;
    __syncthreads();
    for (int off = 1; off < 1024; off <<= 1) {
        int a = (t >= off) ? tmp[t - off] : 0;
        __syncthreads();
        tmp[t] += a;
        __syncthreads();
    }
    int excl = tmp[t] - v;
    int node = b * 1024 + t;
    if (node < N) rowptr[node] = bbase + excl;
    if (b == nbk - 1 && t == 1023) rowptr[N] = E;
    __syncthreads();
    ncnt[t] = excl;
    __syncthreads();
    #pragma unroll
    for (int k = 0; k < EPT; ++k)
        if (dl[k] >= 0) adjstage[ncnt[dl[k]] + rk[k]] = (int)sv[k];
    __syncthreads();
    for (int i = t; i < total; i += 1024)
        adjS[bbase + i] = adjstage[i];
}

// ---- cvt: P0[node][64] = f * x[node][:], f = dis>0 ? dis : 1 (fp16) ----
__global__ void cvt_kernel(const float* __restrict__ x, const float* __restrict__ dis,
                           _Float16* __restrict__ p0, long long n8) {
    long long i = (long long)blockIdx.x * blockDim.x + threadIdx.x;
    if (i < n8) {
        int node = (int)(i >> 3);
        float dv = dis[node];
        float f = (dv > 0.f) ? dv : 1.0f;
        const float4* x4 = reinterpret_cast<const float4*>(x);
        float4 a = x4[i * 2], b = x4[i * 2 + 1];
        f16x8 h;
        h[0] = (_Float16)(f * a.x); h[1] = (_Float16)(f * a.y);
        h[2] = (_Float16)(f * a.z); h[3] = (_Float16)(f * a.w);
        h[4] = (_Float16)(f * b.x); h[5] = (_Float16)(f * b.y);
        h[6] = (_Float16)(f * b.z); h[7] = (_Float16)(f * b.w);
        reinterpret_cast<f16x8*>(p0)[i] = h;
    }
}

// ---- wcvt: pre-swizzle W into fp16 MFMA B-frag layout ----
__global__ void wcvt_kernel(const float* __restrict__ W, _Float16* __restrict__ Wh,
                            int nfrag) {
    int idx = blockIdx.x * blockDim.x + threadIdx.x;
    if (idx >= nfrag) return;
    int lane = idx & 63;
    int ct = (idx >> 6) & 3;
    int kt = (idx >> 8) & 1;
    int k = idx >> 9;
    int r0 = kt * 32 + (lane >> 4) * 8;
    int c = ct * 16 + (lane & 15);
    f16x8 h;
    #pragma unroll
    for (int i = 0; i < 8; ++i)
        h[i] = (_Float16)W[(size_t)k * DD * DD + (size_t)(r0 + i) * DD + c];
    reinterpret_cast<f16x8*>(Wh)[idx] = h;
}

// ---- prop: Pout = scale*dis^2*gathersum(Pin) - Pt0 ----
__global__ __launch_bounds__(256, 8) void prop_kernel(
        const int* __restrict__ rowptr, const int* __restrict__ adjS,
        const float* __restrict__ dis,
        const _Float16* __restrict__ h, const _Float16* t0,
        _Float16* __restrict__ pout, float scale, int N) {
    int t = threadIdx.x;
    int nl = t >> 6, lane = t & 63;
    int q = lane & 7;
    int s = (lane >> 3) & 1;
    int ng = lane >> 4;
    int node = blockIdx.x * NPB + nl * 4 + ng;
    bool valid = node < N;
    const f16x8* h8 = reinterpret_cast<const f16x8*>(h);

    int beg = 0, end = 0;
    if (valid) { beg = rowptr[node]; end = rowptr[node + 1]; }

    float acc[8];
    #pragma unroll
    for (int i = 0; i < 8; ++i) acc[i] = 0.f;

    int j = beg + s;
    int e0 = (j < end) ? adjS[j] : 0;
    int e1 = (j + 2 < end) ? adjS[j + 2] : 0;
    int e2 = (j + 4 < end) ? adjS[j + 4] : 0;
    int e3 = (j + 6 < end) ? adjS[j + 6] : 0;
    float m0 = (j < end) ? 1.f : 0.f;
    float m1 = (j + 2 < end) ? 1.f : 0.f;
    float m2 = (j + 4 < end) ? 1.f : 0.f;
    float m3 = (j + 6 < end) ? 1.f : 0.f;
    while (j < end) {
        int jn = j + 8;
        int n0 = (jn < end) ? adjS[jn] : 0;
        int n1 = (jn + 2 < end) ? adjS[jn + 2] : 0;
        int n2 = (jn + 4 < end) ? adjS[jn + 4] : 0;
        int n3 = (jn + 6 < end) ? adjS[jn + 6] : 0;
        float nm0 = (jn < end) ? 1.f : 0.f;
        float nm1 = (jn + 2 < end) ? 1.f : 0.f;
        float nm2 = (jn + 4 < end) ? 1.f : 0.f;
        float nm3 = (jn + 6 < end) ? 1.f : 0.f;
        f16x8 g0 = h8[(size_t)e0 * 8 + q];
        f16x8 g1 = h8[(size_t)e1 * 8 + q];
        f16x8 g2 = h8[(size_t)e2 * 8 + q];
        f16x8 g3 = h8[(size_t)e3 * 8 + q];
        #pragma unroll
        for (int i = 0; i < 8; ++i) {
            acc[i] += m0 * (float)g0[i] + m1 * (float)g1[i];
            acc[i] += m2 * (float)g2[i] + m3 * (float)g3[i];
        }
        e0 = n0; e1 = n1; e2 = n2; e3 = n3;
        m0 = nm0; m1 = nm1; m2 = nm2; m3 = nm3;
        j = jn;
    }
    #pragma unroll
    for (int i = 0; i < 8; ++i) acc[i] += __shfl_xor(acc[i], 8, 64);

    if (s == 0 && valid) {
        float dv = dis[node];
        float cf = scale * dv * dv;
        size_t base = (size_t)node * DD + q * 8;
        f16x8 vh;
        if (t0) {
            f16x8 t0v = __builtin_nontemporal_load(
                reinterpret_cast<const f16x8*>(t0 + base));
            #pragma unroll
            for (int i = 0; i < 8; ++i)
                vh[i] = (_Float16)(cf * acc[i] - (float)t0v[i]);
        } else {
            #pragma unroll
            for (int i = 0; i < 8; ++i) vh[i] = (_Float16)(cf * acc[i]);
        }
        *reinterpret_cast<f16x8*>(pout + base) = vh;   // plain: keep L2/L3-resident
    }
}

// ---- A-frag: row = node, k = kt*32 + lk*8 + i (contiguous 16B) ----
static __device__ __forceinline__ f16x8 afrag(const _Float16* __restrict__ P,
                                              int node, int kt, int lk) {
    return *reinterpret_cast<const f16x8*>(P + (size_t)node * DD + kt * 32 + lk * 8);
}

// ---- prop_last: P4 = -2 dis^2 gather(P3) - P2 (LDS tile, never written out);
//      out = b + invd*(P0@W0 + P1@W1 + P2@W2 + P3@W3 + P4@W4) ----
__global__ __launch_bounds__(256, 6) void prop_last_kernel(
        const int* __restrict__ rowptr, const int* __restrict__ adjS,
        const float* __restrict__ dis,
        const _Float16* __restrict__ h /*P3*/, const _Float16* __restrict__ t0 /*P2*/,
        const _Float16* __restrict__ P0, const _Float16* __restrict__ P1,
        const _Float16* __restrict__ Wh, const float* __restrict__ bias,
        float* __restrict__ out, int N) {
    __shared__ _Float16 A_lds[NPB][ASTR];
    int t = threadIdx.x;
    int nl = t >> 6, lane = t & 63;
    int q = lane & 7;
    int s = (lane >> 3) & 1;
    int ng = lane >> 4;
    int nb0 = blockIdx.x * NPB;
    int node = nb0 + nl * 4 + ng;
    bool valid = node < N;
    const f16x8* h8 = reinterpret_cast<const f16x8*>(h);

    int beg = 0, end = 0;
    if (valid) { beg = rowptr[node]; end = rowptr[node + 1]; }

    float acc[8];
    #pragma unroll
    for (int i = 0; i < 8; ++i) acc[i] = 0.f;

    int j = beg + s;
    int e0 = (j < end) ? adjS[j] : 0;
    int e1 = (j + 2 < end) ? adjS[j + 2] : 0;
    int e2 = (j + 4 < end) ? adjS[j + 4] : 0;
    int e3 = (j + 6 < end) ? adjS[j + 6] : 0;
    float m0 = (j < end) ? 1.f : 0.f;
    float m1 = (j + 2 < end) ? 1.f : 0.f;
    float m2 = (j + 4 < end) ? 1.f : 0.f;
    float m3 = (j + 6 < end) ? 1.f : 0.f;
    while (j < end) {
        int jn = j + 8;
        int n0 = (jn < end) ? adjS[jn] : 0;
        int n1 = (jn + 2 < end) ? adjS[jn + 2] : 0;
        int n2 = (jn + 4 < end) ? adjS[jn + 4] : 0;
        int n3 = (jn + 6 < end) ? adjS[jn + 6] : 0;
        float nm0 = (jn < end) ? 1.f : 0.f;
        float nm1 = (jn + 2 < end) ? 1.f : 0.f;
        float nm2 = (jn + 4 < end) ? 1.f : 0.f;
        float nm3 = (jn + 6 < end) ? 1.f : 0.f;
        f16x8 g0 = h8[(size_t)e0 * 8 + q];
        f16x8 g1 = h8[(size_t)e1 * 8 + q];
        f16x8 g2 = h8[(size_t)e2 * 8 + q];
        f16x8 g3 = h8[(size_t)e3 * 8 + q];
        #pragma unroll
        for (int i = 0; i < 8; ++i) {
            acc[i] += m0 * (float)g0[i] + m1 * (float)g1[i];
            acc[i] += m2 * (float)g2[i] + m3 * (float)g3[i];
        }
        e0 = n0; e1 = n1; e2 = n2; e3 = n3;
        m0 = nm0; m1 = nm1; m2 = nm2; m3 = nm3;
        j = jn;
    }
    #pragma unroll
    for (int i = 0; i < 8; ++i) acc[i] += __shfl_xor(acc[i], 8, 64);

    if (s == 0 && valid) {
        float dv = dis[node];
        float cf = -2.0f * dv * dv;
        size_t base = (size_t)node * DD + q * 8;
        f16x8 t0v = __builtin_nontemporal_load(
            reinterpret_cast<const f16x8*>(t0 + base));
        f16x8 vh;
        #pragma unroll
        for (int i = 0; i < 8; ++i)
            vh[i] = (_Float16)(cf * acc[i] - (float)t0v[i]);
        *reinterpret_cast<f16x8*>(&A_lds[nl * 4 + ng][q * 8]) = vh;
    }
    __syncthreads();

    // ---- GEMM epilogue: wave nl = col-tile ----
    int ct = nl, lr = lane & 15, lk = lane >> 4;
    const f16x8* Wh8 = reinterpret_cast<const f16x8*>(Wh);
    f16x8 bf[5][2];
    #pragma unroll
    for (int k = 0; k < 5; ++k)
        #pragma unroll
        for (int kt = 0; kt < 2; ++kt)
            bf[k][kt] = Wh8[((k * 2 + kt) * 4 + ct) * 64 + lane];
    int gn = min(nb0 + lr, N - 1);
    f32x4 d = {0.f, 0.f, 0.f, 0.f};
    #pragma unroll
    for (int kt = 0; kt < 2; ++kt) {
        f16x8 a4 = *reinterpret_cast<const f16x8*>(&A_lds[lr][kt * 32 + lk * 8]);
        d = __builtin_amdgcn_mfma_f32_16x16x32_f16(afrag(P0, gn, kt, lk), bf[0][kt], d, 0, 0, 0);
        d = __builtin_amdgcn_mfma_f32_16x16x32_f16(afrag(P1, gn, kt, lk), bf[1][kt], d, 0, 0, 0);
        d = __builtin_amdgcn_mfma_f32_16x16x32_f16(afrag(t0, gn, kt, lk), bf[2][kt], d, 0, 0, 0);
        d = __builtin_amdgcn_mfma_f32_16x16x32_f16(afrag(h,  gn, kt, lk), bf[3][kt], d, 0, 0, 0);
        d = __builtin_amdgcn_mfma_f32_16x16x32_f16(a4, bf[4][kt], d, 0, 0, 0);
    }
    int nvb = min(NPB, N - nb0);
    int col = ct * 16 + lr;
    float bv = bias[col];
    #pragma unroll
    for (int r = 0; r < 4; ++r) {
        int row = lk * 4 + r;
        if (row < nvb) {
            float dv = dis[nb0 + row];
            float invd = (dv > 0.f) ? 1.f / dv : 1.f;
            long long o = (long long)(nb0 + row) * DD + col;
            __builtin_nontemporal_store(bv + invd * d[r], out + o);
        }
    }
}

// ---- gemm2 (fallback): out = b + invd*(P0@W0 + P1@W1) ----
__global__ __launch_bounds__(256, 8) void gemm2_kernel(
        const _Float16* __restrict__ P0, const _Float16* __restrict__ P1,
        const float* __restrict__ dis,
        const float* __restrict__ W0, const float* __restrict__ W1,
        const float* __restrict__ bias, float* __restrict__ out, int N) {
    int t = threadIdx.x;
    int nl = t >> 6, lane = t & 63;
    int ct = nl, lr = lane & 15, lk = lane >> 4;
    f16x8 bf0[2], bf1[2];
    #pragma unroll
    for (int kt = 0; kt < 2; ++kt)
        #pragma unroll
        for (int i = 0; i < 8; ++i) {
            int r = kt * 32 + lk * 8 + i;
            bf0[kt][i] = (_Float16)W0[r * DD + ct * 16 + lr];
            bf1[kt][i] = (_Float16)W1[r * DD + ct * 16 + lr];
        }
    int nb0 = blockIdx.x * NPB;
    int node = min(nb0 + lr, N - 1);
    f32x4 d = {0.f, 0.f, 0.f, 0.f};
    #pragma unroll
    for (int kt = 0; kt < 2; ++kt) {
        d = __builtin_amdgcn_mfma_f32_16x16x32_f16(afrag(P0, node, kt, lk), bf0[kt], d, 0, 0, 0);
        d = __builtin_amdgcn_mfma_f32_16x16x32_f16(afrag(P1, node, kt, lk), bf1[kt], d, 0, 0, 0);
    }
    int nvb = min(NPB, N - nb0);
    int col = ct * 16 + lr;
    float bv = bias[col];
    #pragma unroll
    for (int r = 0; r < 4; ++r) {
        int row = lk * 4 + r;
        if (row < nvb) {
            float dv = dis[nb0 + row];
            float invd = (dv > 0.f) ? 1.f / dv : 1.f;
            long long o = (long long)(nb0 + row) * DD + col;
            out[o] = bv + invd * d[r];
        }
    }
}

// ---- gemm1 (fallback): out += invd*(P@Wk) ----
__global__ __launch_bounds__(256, 8) void gemm1_kernel(
        const _Float16* __restrict__ P, const float* __restrict__ dis,
        const float* __restrict__ Wk, float* __restrict__ out, int N) {
    int t = threadIdx.x;
    int nl = t >> 6, lane = t & 63;
    int ct = nl, lr = lane & 15, lk = lane >> 4;
    f16x8 bf[2];
    #pragma unroll
    for (int kt = 0; kt < 2; ++kt)
        #pragma unroll
        for (int i = 0; i < 8; ++i) {
            int r = kt * 32 + lk * 8 + i;
            bf[kt][i] = (_Float16)Wk[r * DD + ct * 16 + lr];
        }
    int nb0 = blockIdx.x * NPB;
    int node = min(nb0 + lr, N - 1);
    f32x4 d = {0.f, 0.f, 0.f, 0.f};
    #pragma unroll
    for (int kt = 0; kt < 2; ++kt)
        d = __builtin_amdgcn_mfma_f32_16x16x32_f16(afrag(P, node, kt, lk), bf[kt], d, 0, 0, 0);
    int nvb = min(NPB, N - nb0);
    int col = ct * 16 + lr;
    #pragma unroll
    for (int r = 0; r < 4; ++r) {
        int row = lk * 4 + r;
        if (row < nvb) {
            float dv = dis[nb0 + row];
            float invd = (dv > 0.f) ? 1.f / dv : 1.f;
            long long o = (long long)(nb0 + row) * DD + col;
            out[o] = out[o] + invd * d[r];
        }
    }
}

extern "C" void kernel_launch(void* const* d_in, const int* in_sizes, int n_in,
                              void* d_out, int out_size, void* d_ws, size_t ws_size,
                              hipStream_t stream) {
    const float* x  = (const float*)d_in[0];
    const int*   ei = (const int*)d_in[1];
    const float* W  = (const float*)d_in[2];
    const float* b  = (const float*)d_in[3];
    float* out = (float*)d_out;

    const int N = in_sizes[0] / DD;
    const int E = in_sizes[1] / 2;
    const int K = in_sizes[2] / (DD * DD);
    const long long ND = (long long)N * DD;
    const int NR = ((N + 3) / 4) * 4;
    const int nbk = (N + 1023) >> 10;             // coarse buckets (<= NBKMAX)

    const int* src = ei;
    const int* dst = ei + E;

    size_t off = 0;
    char* base = (char*)d_ws;
    auto alloc = [&](size_t bytes) {
        char* p = base + off;
        off = (off + bytes + 63) & ~(size_t)63;
        return p;
    };
    float* dis = (float*)alloc((size_t)N * 4);
    int* rowptr = (int*)alloc((size_t)(N + 1) * 4);
    _Float16* Wh = (_Float16*)alloc((size_t)5 * 2 * 4 * 64 * 8 * 2);
    int* gbcnt = (int*)alloc((size_t)NBKMAX * 4);
    // overlay region: srcp partials + bktbuf (dead after csrB/disred) host P2 later
    char* ovl = alloc((size_t)NBS * NR + (size_t)NBKMAX * CAPB * 4);
    unsigned char* srcp = (unsigned char*)ovl;
    unsigned int* bktbuf = (unsigned int*)(ovl + (size_t)NBS * NR);
    int* adjS = (int*)alloc((size_t)E * 4);
    _Float16* P0 = (_Float16*)alloc((size_t)ND * 2);
    _Float16* P1 = (_Float16*)alloc((size_t)ND * 2);
    _Float16* P3 = (_Float16*)alloc((size_t)ND * 2);
    _Float16* P2 = (_Float16*)ovl;      // overlays srcp+bktbuf after they're dead

    (void)hipMemsetAsync(gbcnt, 0, (size_t)NBKMAX * 4, stream);

    const int sliceS = (E + NBS - 1) / NBS;
    histS_kernel<<<NBS, 1024, (size_t)NR, stream>>>(src, srcp, N, NR, E, sliceS);
    disred_kernel<<<(N + 255) / 256, 256, 0, stream>>>(srcp, dis, N, NR);

    const int na = (E + EPB * 1024 - 1) / (EPB * 1024);
    histA_kernel<<<na, 1024, 0, stream>>>(src, dst, gbcnt, bktbuf, E, nbk);
    csrB_kernel<<<nbk, 1024, 0, stream>>>(bktbuf, gbcnt, rowptr, adjS, N, nbk, E);

    const long long n8 = ND / 8;
    cvt_kernel<<<(int)((n8 + 255) / 256), 256, 0, stream>>>(x, dis, P0, n8);
    if (K == 5) {
        const int nfrag = 5 * 2 * 4 * 64;
        wcvt_kernel<<<(nfrag + 255) / 256, 256, 0, stream>>>(W, Wh, nfrag);
    }

    const int pgrid = (N + NPB - 1) / NPB;
    const int Wsz = DD * DD;

    if (K == 5) {
        prop_kernel<<<pgrid, 256, 0, stream>>>(rowptr, adjS, dis, P0,
                                               (const _Float16*)0, P1, -1.0f, N);
        prop_kernel<<<pgrid, 256, 0, stream>>>(rowptr, adjS, dis, P1, P0, P2, -2.0f, N);
        prop_kernel<<<pgrid, 256, 0, stream>>>(rowptr, adjS, dis, P2, P1, P3, -2.0f, N);
        // P4 in-LDS + full GEMM epilogue (out write-only)
        prop_last_kernel<<<pgrid, 256, 0, stream>>>(rowptr, adjS, dis, P3, P2,
                                                    P0, P1, Wh, b, out, N);
    } else {
        prop_kernel<<<pgrid, 256, 0, stream>>>(rowptr, adjS, dis, P0,
                                               (const _Float16*)0, P1, -1.0f, N);
        gemm2_kernel<<<pgrid, 256, 0, stream>>>(P0, P1, dis, W, W + Wsz, b, out, N);
        _Float16* t0 = P0;
        _Float16* h  = P1;
        _Float16* fr = P2;
        for (int k = 2; k < K; ++k) {
            prop_kernel<<<pgrid, 256, 0, stream>>>(rowptr, adjS, dis, h, t0, fr, -2.0f, N);
            gemm1_kernel<<<pgrid, 256, 0, stream>>>(fr, dis, W + (long long)k * Wsz,
                                                    out, N);
            _Float16* nfree = t0;
            t0 = h; h = fr; fr = nfree;
        }
    }
}

// Round 23
// 313.086 us; speedup vs baseline: 1.0966x; 1.0076x over previous
//
#include <hip/hip_runtime.h>

#define DD 64
#define NPB 16     // nodes per tile (4 waves x 4 concurrent nodes in prop)
#define NBS 128    // histS partial-histogram blocks
#define NBKMAX 128 // max coarse buckets (N <= 131072)
#define CAPB 20480 // bucket capacity (mean 16384 + 32 sigma)
#define EPB 8      // edges per thread in histA
#define EPT 20     // entries per thread in csrB (CAPB/1024)
#define ASTR 72    // halves per LDS A-tile row (64 + 8 pad)

typedef _Float16 f16x8 __attribute__((ext_vector_type(8)));
typedef float f32x4 __attribute__((ext_vector_type(4)));

// ---- histS: per-block LDS u8 histogram of src (for degrees) ----
__global__ __launch_bounds__(1024) void histS_kernel(
        const int* __restrict__ src, unsigned char* __restrict__ srcp,
        int N, int NR, int E, int slice) {
    extern __shared__ unsigned int ldsH[];
    int nw = NR >> 2;
    int t = threadIdx.x;
    for (int i = t; i < nw; i += 1024) ldsH[i] = 0u;
    __syncthreads();
    int base = blockIdx.x * slice;
    int end = min(base + slice, E);
    for (int e = base + t; e < end; e += 1024) {
        int s = __builtin_nontemporal_load(src + e);
        atomicAdd(&ldsH[s >> 2], 1u << ((unsigned int)(s & 3) * 8u));
    }
    __syncthreads();
    unsigned int* outp = reinterpret_cast<unsigned int*>(srcp + (size_t)blockIdx.x * NR);
    for (int i = t; i < nw; i += 1024) outp[i] = ldsH[i];
}

// ---- cvt: fused degree-reduce + dis + P0 = f*x (fp16) ----
// Block = 256 threads = 32 nodes. Phase 1: 8 threads/node sum 16 partial rows
// each, shfl-reduce, write dis + LDS scale. Phase 2: convert 32 rows.
__global__ __launch_bounds__(256) void cvt_kernel(
        const float* __restrict__ x, const unsigned char* __restrict__ srcp,
        float* __restrict__ dis, _Float16* __restrict__ p0, int N, int NR) {
    __shared__ float fs[32];
    int t = threadIdx.x;
    int nloc = t >> 3;                 // node within block, 0..31
    int part = t & 7;
    int node = blockIdx.x * 32 + nloc;
    int degv = 0;
    if (node < N) {
        #pragma unroll 4
        for (int i = part * (NBS / 8); i < (part + 1) * (NBS / 8); ++i)
            degv += srcp[(size_t)i * NR + node];
    }
    degv += __shfl_xor(degv, 1, 64);
    degv += __shfl_xor(degv, 2, 64);
    degv += __shfl_xor(degv, 4, 64);
    if (part == 0 && node < N) {
        float dv = (degv > 0) ? rsqrtf((float)degv) : 0.0f;
        dis[node] = dv;
        fs[nloc] = (dv > 0.f) ? dv : 1.0f;
    }
    __syncthreads();
    if (node >= N) return;
    float f = fs[nloc];
    // chunk = part: halves 8*part..8*part+7 of this node's row
    const float4* x4 = reinterpret_cast<const float4*>(x);
    long long xi = (long long)node * 16 + part * 2;
    float4 a = x4[xi], b = x4[xi + 1];
    f16x8 h;
    h[0] = (_Float16)(f * a.x); h[1] = (_Float16)(f * a.y);
    h[2] = (_Float16)(f * a.z); h[3] = (_Float16)(f * a.w);
    h[4] = (_Float16)(f * b.x); h[5] = (_Float16)(f * b.y);
    h[6] = (_Float16)(f * b.z); h[7] = (_Float16)(f * b.w);
    *reinterpret_cast<f16x8*>(p0 + (size_t)node * DD + part * 8) = h;
}

// ---- histA: coarse dst-bucket scatter (bucket = dst>>10) ----
__global__ __launch_bounds__(1024) void histA_kernel(
        const int* __restrict__ src, const int* __restrict__ dst,
        int* __restrict__ gbcnt, unsigned int* __restrict__ bktbuf,
        int E, int nbk) {
    __shared__ int lcnt[NBKMAX];
    __shared__ int lbase[NBKMAX];
    int t = threadIdx.x;
    if (t < NBKMAX) lcnt[t] = 0;
    __syncthreads();
    int base = blockIdx.x * (EPB * 1024);
    unsigned int ent[EPB];
    int rk[EPB];
    int bk[EPB];
    #pragma unroll
    for (int k = 0; k < EPB; ++k) {
        int e = base + t + k * 1024;
        bk[k] = -1;
        if (e < E) {
            int s = __builtin_nontemporal_load(src + e);
            int d = __builtin_nontemporal_load(dst + e);
            int b = d >> 10;
            ent[k] = ((unsigned int)s << 10) | (unsigned int)(d & 1023);
            rk[k] = atomicAdd(&lcnt[b], 1);
            bk[k] = b;
        }
    }
    __syncthreads();
    if (t < nbk) lbase[t] = atomicAdd(&gbcnt[t], lcnt[t]);
    __syncthreads();
    #pragma unroll
    for (int k = 0; k < EPB; ++k) {
        if (bk[k] >= 0) {
            int pos = lbase[bk[k]] + rk[k];
            if (pos < CAPB)
                __builtin_nontemporal_store(ent[k],
                    bktbuf + (size_t)bk[k] * CAPB + pos);
        }
    }
}

// ---- csrB: per-bucket CSR build entirely in LDS; coalesced adjS writeout ----
__global__ __launch_bounds__(1024) void csrB_kernel(
        const unsigned int* __restrict__ bktbuf, const int* __restrict__ gbcnt,
        int* __restrict__ rowptr, int* __restrict__ adjS,
        int N, int nbk, int E) {
    __shared__ int ncnt[1024];
    __shared__ int tmp[1024];
    __shared__ int adjstage[CAPB];
    __shared__ int gb[NBKMAX];
    __shared__ int bbase_s;
    int b = blockIdx.x;
    int t = threadIdx.x;
    if (t < NBKMAX) gb[t] = (t < nbk) ? gbcnt[t] : 0;
    ncnt[t] = 0;
    __syncthreads();
    if (t == 0) {
        int acc = 0;
        for (int i = 0; i < b; ++i) acc += gb[i];
        bbase_s = acc;
    }
    __syncthreads();
    int total = min(gb[b], CAPB);
    int bbase = bbase_s;
    const unsigned int* bp = bktbuf + (size_t)b * CAPB;
    unsigned int sv[EPT];
    int rk[EPT];
    int dl[EPT];
    #pragma unroll
    for (int k = 0; k < EPT; ++k) {
        int i = t + k * 1024;
        dl[k] = -1;
        if (i < total) {
            unsigned int v = bp[i];
            sv[k] = v >> 10;
            int d = (int)(v & 1023u);
            dl[k] = d;
            rk[k] = atomicAdd(&ncnt[d], 1);
        }
    }
    __syncthreads();
    int v = ncnt[t];
    tmp[t] = v;
    __syncthreads();
    for (int off = 1; off < 1024; off <<= 1) {
        int a = (t >= off) ? tmp[t - off] : 0;
        __syncthreads();
        tmp[t] += a;
        __syncthreads();
    }
    int excl = tmp[t] - v;
    int node = b * 1024 + t;
    if (node < N) rowptr[node] = bbase + excl;
    if (b == nbk - 1 && t == 1023) rowptr[N] = E;
    __syncthreads();
    ncnt[t] = excl;
    __syncthreads();
    #pragma unroll
    for (int k = 0; k < EPT; ++k)
        if (dl[k] >= 0) adjstage[ncnt[dl[k]] + rk[k]] = (int)sv[k];
    __syncthreads();
    for (int i = t; i < total; i += 1024)
        adjS[bbase + i] = adjstage[i];
}

// ---- wcvt: pre-swizzle W into fp16 MFMA B-frag layout ----
__global__ void wcvt_kernel(const float* __restrict__ W, _Float16* __restrict__ Wh,
                            int nfrag) {
    int idx = blockIdx.x * blockDim.x + threadIdx.x;
    if (idx >= nfrag) return;
    int lane = idx & 63;
    int ct = (idx >> 6) & 3;
    int kt = (idx >> 8) & 1;
    int k = idx >> 9;
    int r0 = kt * 32 + (lane >> 4) * 8;
    int c = ct * 16 + (lane & 15);
    f16x8 h;
    #pragma unroll
    for (int i = 0; i < 8; ++i)
        h[i] = (_Float16)W[(size_t)k * DD * DD + (size_t)(r0 + i) * DD + c];
    reinterpret_cast<f16x8*>(Wh)[idx] = h;
}

// ---- prop: Pout = scale*dis^2*gathersum(Pin) - Pt0 ----
__global__ __launch_bounds__(256, 8) void prop_kernel(
        const int* __restrict__ rowptr, const int* __restrict__ adjS,
        const float* __restrict__ dis,
        const _Float16* __restrict__ h, const _Float16* t0,
        _Float16* __restrict__ pout, float scale, int N) {
    int t = threadIdx.x;
    int nl = t >> 6, lane = t & 63;
    int q = lane & 7;
    int s = (lane >> 3) & 1;
    int ng = lane >> 4;
    int node = blockIdx.x * NPB + nl * 4 + ng;
    bool valid = node < N;
    const f16x8* h8 = reinterpret_cast<const f16x8*>(h);

    int beg = 0, end = 0;
    if (valid) { beg = rowptr[node]; end = rowptr[node + 1]; }

    float acc[8];
    #pragma unroll
    for (int i = 0; i < 8; ++i) acc[i] = 0.f;

    int j = beg + s;
    int e0 = (j < end) ? adjS[j] : 0;
    int e1 = (j + 2 < end) ? adjS[j + 2] : 0;
    int e2 = (j + 4 < end) ? adjS[j + 4] : 0;
    int e3 = (j + 6 < end) ? adjS[j + 6] : 0;
    float m0 = (j < end) ? 1.f : 0.f;
    float m1 = (j + 2 < end) ? 1.f : 0.f;
    float m2 = (j + 4 < end) ? 1.f : 0.f;
    float m3 = (j + 6 < end) ? 1.f : 0.f;
    while (j < end) {
        int jn = j + 8;
        int n0 = (jn < end) ? adjS[jn] : 0;
        int n1 = (jn + 2 < end) ? adjS[jn + 2] : 0;
        int n2 = (jn + 4 < end) ? adjS[jn + 4] : 0;
        int n3 = (jn + 6 < end) ? adjS[jn + 6] : 0;
        float nm0 = (jn < end) ? 1.f : 0.f;
        float nm1 = (jn + 2 < end) ? 1.f : 0.f;
        float nm2 = (jn + 4 < end) ? 1.f : 0.f;
        float nm3 = (jn + 6 < end) ? 1.f : 0.f;
        f16x8 g0 = h8[(size_t)e0 * 8 + q];
        f16x8 g1 = h8[(size_t)e1 * 8 + q];
        f16x8 g2 = h8[(size_t)e2 * 8 + q];
        f16x8 g3 = h8[(size_t)e3 * 8 + q];
        #pragma unroll
        for (int i = 0; i < 8; ++i) {
            acc[i] += m0 * (float)g0[i] + m1 * (float)g1[i];
            acc[i] += m2 * (float)g2[i] + m3 * (float)g3[i];
        }
        e0 = n0; e1 = n1; e2 = n2; e3 = n3;
        m0 = nm0; m1 = nm1; m2 = nm2; m3 = nm3;
        j = jn;
    }
    #pragma unroll
    for (int i = 0; i < 8; ++i) acc[i] += __shfl_xor(acc[i], 8, 64);

    if (s == 0 && valid) {
        float dv = dis[node];
        float cf = scale * dv * dv;
        size_t base = (size_t)node * DD + q * 8;
        f16x8 vh;
        if (t0) {
            f16x8 t0v = __builtin_nontemporal_load(
                reinterpret_cast<const f16x8*>(t0 + base));
            #pragma unroll
            for (int i = 0; i < 8; ++i)
                vh[i] = (_Float16)(cf * acc[i] - (float)t0v[i]);
        } else {
            #pragma unroll
            for (int i = 0; i < 8; ++i) vh[i] = (_Float16)(cf * acc[i]);
        }
        *reinterpret_cast<f16x8*>(pout + base) = vh;   // plain: keep L2/L3-resident
    }
}

// ---- A-frag: row = node, k = kt*32 + lk*8 + i (contiguous 16B) ----
static __device__ __forceinline__ f16x8 afrag(const _Float16* __restrict__ P,
                                              int node, int kt, int lk) {
    return *reinterpret_cast<const f16x8*>(P + (size_t)node * DD + kt * 32 + lk * 8);
}

// ---- prop_last: P4 = -2 dis^2 gather(P3) - P2 (LDS tile, never written out);
//      out = b + invd*(P0@W0 + P1@W1 + P2@W2 + P3@W3 + P4@W4) ----
__global__ __launch_bounds__(256, 6) void prop_last_kernel(
        const int* __restrict__ rowptr, const int* __restrict__ adjS,
        const float* __restrict__ dis,
        const _Float16* __restrict__ h /*P3*/, const _Float16* __restrict__ t0 /*P2*/,
        const _Float16* __restrict__ P0, const _Float16* __restrict__ P1,
        const _Float16* __restrict__ Wh, const float* __restrict__ bias,
        float* __restrict__ out, int N) {
    __shared__ _Float16 A_lds[NPB][ASTR];
    int t = threadIdx.x;
    int nl = t >> 6, lane = t & 63;
    int q = lane & 7;
    int s = (lane >> 3) & 1;
    int ng = lane >> 4;
    int nb0 = blockIdx.x * NPB;
    int node = nb0 + nl * 4 + ng;
    bool valid = node < N;
    const f16x8* h8 = reinterpret_cast<const f16x8*>(h);

    int beg = 0, end = 0;
    if (valid) { beg = rowptr[node]; end = rowptr[node + 1]; }

    float acc[8];
    #pragma unroll
    for (int i = 0; i < 8; ++i) acc[i] = 0.f;

    int j = beg + s;
    int e0 = (j < end) ? adjS[j] : 0;
    int e1 = (j + 2 < end) ? adjS[j + 2] : 0;
    int e2 = (j + 4 < end) ? adjS[j + 4] : 0;
    int e3 = (j + 6 < end) ? adjS[j + 6] : 0;
    float m0 = (j < end) ? 1.f : 0.f;
    float m1 = (j + 2 < end) ? 1.f : 0.f;
    float m2 = (j + 4 < end) ? 1.f : 0.f;
    float m3 = (j + 6 < end) ? 1.f : 0.f;
    while (j < end) {
        int jn = j + 8;
        int n0 = (jn < end) ? adjS[jn] : 0;
        int n1 = (jn + 2 < end) ? adjS[jn + 2] : 0;
        int n2 = (jn + 4 < end) ? adjS[jn + 4] : 0;
        int n3 = (jn + 6 < end) ? adjS[jn + 6] : 0;
        float nm0 = (jn < end) ? 1.f : 0.f;
        float nm1 = (jn + 2 < end) ? 1.f : 0.f;
        float nm2 = (jn + 4 < end) ? 1.f : 0.f;
        float nm3 = (jn + 6 < end) ? 1.f : 0.f;
        f16x8 g0 = h8[(size_t)e0 * 8 + q];
        f16x8 g1 = h8[(size_t)e1 * 8 + q];
        f16x8 g2 = h8[(size_t)e2 * 8 + q];
        f16x8 g3 = h8[(size_t)e3 * 8 + q];
        #pragma unroll
        for (int i = 0; i < 8; ++i) {
            acc[i] += m0 * (float)g0[i] + m1 * (float)g1[i];
            acc[i] += m2 * (float)g2[i] + m3 * (float)g3[i];
        }
        e0 = n0; e1 = n1; e2 = n2; e3 = n3;
        m0 = nm0; m1 = nm1; m2 = nm2; m3 = nm3;
        j = jn;
    }
    #pragma unroll
    for (int i = 0; i < 8; ++i) acc[i] += __shfl_xor(acc[i], 8, 64);

    if (s == 0 && valid) {
        float dv = dis[node];
        float cf = -2.0f * dv * dv;
        size_t base = (size_t)node * DD + q * 8;
        f16x8 t0v = __builtin_nontemporal_load(
            reinterpret_cast<const f16x8*>(t0 + base));
        f16x8 vh;
        #pragma unroll
        for (int i = 0; i < 8; ++i)
            vh[i] = (_Float16)(cf * acc[i] - (float)t0v[i]);
        *reinterpret_cast<f16x8*>(&A_lds[nl * 4 + ng][q * 8]) = vh;
    }
    __syncthreads();

    // ---- GEMM epilogue: wave nl = col-tile ----
    int ct = nl, lr = lane & 15, lk = lane >> 4;
    const f16x8* Wh8 = reinterpret_cast<const f16x8*>(Wh);
    f16x8 bf[5][2];
    #pragma unroll
    for (int k = 0; k < 5; ++k)
        #pragma unroll
        for (int kt = 0; kt < 2; ++kt)
            bf[k][kt] = Wh8[((k * 2 + kt) * 4 + ct) * 64 + lane];
    int gn = min(nb0 + lr, N - 1);
    f32x4 d = {0.f, 0.f, 0.f, 0.f};
    #pragma unroll
    for (int kt = 0; kt < 2; ++kt) {
        f16x8 a4 = *reinterpret_cast<const f16x8*>(&A_lds[lr][kt * 32 + lk * 8]);
        d = __builtin_amdgcn_mfma_f32_16x16x32_f16(afrag(P0, gn, kt, lk), bf[0][kt], d, 0, 0, 0);
        d = __builtin_amdgcn_mfma_f32_16x16x32_f16(afrag(P1, gn, kt, lk), bf[1][kt], d, 0, 0, 0);
        d = __builtin_amdgcn_mfma_f32_16x16x32_f16(afrag(t0, gn, kt, lk), bf[2][kt], d, 0, 0, 0);
        d = __builtin_amdgcn_mfma_f32_16x16x32_f16(afrag(h,  gn, kt, lk), bf[3][kt], d, 0, 0, 0);
        d = __builtin_amdgcn_mfma_f32_16x16x32_f16(a4, bf[4][kt], d, 0, 0, 0);
    }
    int nvb = min(NPB, N - nb0);
    int col = ct * 16 + lr;
    float bv = bias[col];
    #pragma unroll
    for (int r = 0; r < 4; ++r) {
        int row = lk * 4 + r;
        if (row < nvb) {
            float dv = dis[nb0 + row];
            float invd = (dv > 0.f) ? 1.f / dv : 1.f;
            long long o = (long long)(nb0 + row) * DD + col;
            __builtin_nontemporal_store(bv + invd * d[r], out + o);
        }
    }
}

// ---- gemm2 (fallback): out = b + invd*(P0@W0 + P1@W1) ----
__global__ __launch_bounds__(256, 8) void gemm2_kernel(
        const _Float16* __restrict__ P0, const _Float16* __restrict__ P1,
        const float* __restrict__ dis,
        const float* __restrict__ W0, const float* __restrict__ W1,
        const float* __restrict__ bias, float* __restrict__ out, int N) {
    int t = threadIdx.x;
    int nl = t >> 6, lane = t & 63;
    int ct = nl, lr = lane & 15, lk = lane >> 4;
    f16x8 bf0[2], bf1[2];
    #pragma unroll
    for (int kt = 0; kt < 2; ++kt)
        #pragma unroll
        for (int i = 0; i < 8; ++i) {
            int r = kt * 32 + lk * 8 + i;
            bf0[kt][i] = (_Float16)W0[r * DD + ct * 16 + lr];
            bf1[kt][i] = (_Float16)W1[r * DD + ct * 16 + lr];
        }
    int nb0 = blockIdx.x * NPB;
    int node = min(nb0 + lr, N - 1);
    f32x4 d = {0.f, 0.f, 0.f, 0.f};
    #pragma unroll
    for (int kt = 0; kt < 2; ++kt) {
        d = __builtin_amdgcn_mfma_f32_16x16x32_f16(afrag(P0, node, kt, lk), bf0[kt], d, 0, 0, 0);
        d = __builtin_amdgcn_mfma_f32_16x16x32_f16(afrag(P1, node, kt, lk), bf1[kt], d, 0, 0, 0);
    }
    int nvb = min(NPB, N - nb0);
    int col = ct * 16 + lr;
    float bv = bias[col];
    #pragma unroll
    for (int r = 0; r < 4; ++r) {
        int row = lk * 4 + r;
        if (row < nvb) {
            float dv = dis[nb0 + row];
            float invd = (dv > 0.f) ? 1.f / dv : 1.f;
            long long o = (long long)(nb0 + row) * DD + col;
            out[o] = bv + invd * d[r];
        }
    }
}

// ---- gemm1 (fallback): out += invd*(P@Wk) ----
__global__ __launch_bounds__(256, 8) void gemm1_kernel(
        const _Float16* __restrict__ P, const float* __restrict__ dis,
        const float* __restrict__ Wk, float* __restrict__ out, int N) {
    int t = threadIdx.x;
    int nl = t >> 6, lane = t & 63;
    int ct = nl, lr = lane & 15, lk = lane >> 4;
    f16x8 bf[2];
    #pragma unroll
    for (int kt = 0; kt < 2; ++kt)
        #pragma unroll
        for (int i = 0; i < 8; ++i) {
            int r = kt * 32 + lk * 8 + i;
            bf[kt][i] = (_Float16)Wk[r * DD + ct * 16 + lr];
        }
    int nb0 = blockIdx.x * NPB;
    int node = min(nb0 + lr, N - 1);
    f32x4 d = {0.f, 0.f, 0.f, 0.f};
    #pragma unroll
    for (int kt = 0; kt < 2; ++kt)
        d = __builtin_amdgcn_mfma_f32_16x16x32_f16(afrag(P, node, kt, lk), bf[kt], d, 0, 0, 0);
    int nvb = min(NPB, N - nb0);
    int col = ct * 16 + lr;
    #pragma unroll
    for (int r = 0; r < 4; ++r) {
        int row = lk * 4 + r;
        if (row < nvb) {
            float dv = dis[nb0 + row];
            float invd = (dv > 0.f) ? 1.f / dv : 1.f;
            long long o = (long long)(nb0 + row) * DD + col;
            out[o] = out[o] + invd * d[r];
        }
    }
}

extern "C" void kernel_launch(void* const* d_in, const int* in_sizes, int n_in,
                              void* d_out, int out_size, void* d_ws, size_t ws_size,
                              hipStream_t stream) {
    const float* x  = (const float*)d_in[0];
    const int*   ei = (const int*)d_in[1];
    const float* W  = (const float*)d_in[2];
    const float* b  = (const float*)d_in[3];
    float* out = (float*)d_out;

    const int N = in_sizes[0] / DD;
    const int E = in_sizes[1] / 2;
    const int K = in_sizes[2] / (DD * DD);
    const long long ND = (long long)N * DD;
    const int NR = ((N + 3) / 4) * 4;
    const int nbk = (N + 1023) >> 10;             // coarse buckets (<= NBKMAX)

    const int* src = ei;
    const int* dst = ei + E;

    size_t off = 0;
    char* base = (char*)d_ws;
    auto alloc = [&](size_t bytes) {
        char* p = base + off;
        off = (off + bytes + 63) & ~(size_t)63;
        return p;
    };
    float* dis = (float*)alloc((size_t)N * 4);
    int* rowptr = (int*)alloc((size_t)(N + 1) * 4);
    _Float16* Wh = (_Float16*)alloc((size_t)5 * 2 * 4 * 64 * 8 * 2);
    int* gbcnt = (int*)alloc((size_t)NBKMAX * 4);
    // overlay region: srcp partials + bktbuf (dead after csrB/cvt) host P2 later
    char* ovl = alloc((size_t)NBS * NR + (size_t)NBKMAX * CAPB * 4);
    unsigned char* srcp = (unsigned char*)ovl;
    unsigned int* bktbuf = (unsigned int*)(ovl + (size_t)NBS * NR);
    int* adjS = (int*)alloc((size_t)E * 4);
    _Float16* P0 = (_Float16*)alloc((size_t)ND * 2);
    _Float16* P1 = (_Float16*)alloc((size_t)ND * 2);
    _Float16* P3 = (_Float16*)alloc((size_t)ND * 2);
    _Float16* P2 = (_Float16*)ovl;      // overlays srcp+bktbuf after they're dead

    (void)hipMemsetAsync(gbcnt, 0, (size_t)NBKMAX * 4, stream);

    const int sliceS = (E + NBS - 1) / NBS;
    histS_kernel<<<NBS, 1024, (size_t)NR, stream>>>(src, srcp, N, NR, E, sliceS);
    // fused degree-reduce + dis + P0 conversion
    cvt_kernel<<<(N + 31) / 32, 256, 0, stream>>>(x, srcp, dis, P0, N, NR);

    const int na = (E + EPB * 1024 - 1) / (EPB * 1024);
    histA_kernel<<<na, 1024, 0, stream>>>(src, dst, gbcnt, bktbuf, E, nbk);
    csrB_kernel<<<nbk, 1024, 0, stream>>>(bktbuf, gbcnt, rowptr, adjS, N, nbk, E);

    if (K == 5) {
        const int nfrag = 5 * 2 * 4 * 64;
        wcvt_kernel<<<(nfrag + 255) / 256, 256, 0, stream>>>(W, Wh, nfrag);
    }

    const int pgrid = (N + NPB - 1) / NPB;
    const int Wsz = DD * DD;

    if (K == 5) {
        prop_kernel<<<pgrid, 256, 0, stream>>>(rowptr, adjS, dis, P0,
                                               (const _Float16*)0, P1, -1.0f, N);
        prop_kernel<<<pgrid, 256, 0, stream>>>(rowptr, adjS, dis, P1, P0, P2, -2.0f, N);
        prop_kernel<<<pgrid, 256, 0, stream>>>(rowptr, adjS, dis, P2, P1, P3, -2.0f, N);
        // P4 in-LDS + full GEMM epilogue (out write-only)
        prop_last_kernel<<<pgrid, 256, 0, stream>>>(rowptr, adjS, dis, P3, P2,
                                                    P0, P1, Wh, b, out, N);
    } else {
        prop_kernel<<<pgrid, 256, 0, stream>>>(rowptr, adjS, dis, P0,
                                               (const _Float16*)0, P1, -1.0f, N);
        gemm2_kernel<<<pgrid, 256, 0, stream>>>(P0, P1, dis, W, W + Wsz, b, out, N);
        _Float16* t0 = P0;
        _Float16* h  = P1;
        _Float16* fr = P2;
        for (int k = 2; k < K; ++k) {
            prop_kernel<<<pgrid, 256, 0, stream>>>(rowptr, adjS, dis, h, t0, fr, -2.0f, N);
            gemm1_kernel<<<pgrid, 256, 0, stream>>>(fr, dis, W + (long long)k * Wsz,
                                                    out, N);
            _Float16* nfree = t0;
            t0 = h; h = fr; fr = nfree;
        }
    }
}